// Round 1
// baseline (55.709 us; speedup 1.0000x reference)
//
#include <hip/hip_runtime.h>
#include <math.h>

// Problem dims (fixed by setup_inputs)
#define NROWS 8192   // B*T = 4*2048
#define DD    1024
#define HH    256
#define NTT   32
#define NCOLS 288    // HH + NTT

typedef __attribute__((ext_vector_type(8))) __bf16 bf16x8;
typedef __attribute__((ext_vector_type(4))) float f32x4;

static __device__ __forceinline__ unsigned short f2bf(float f) {
    unsigned int u = __float_as_uint(f);
    unsigned int r = (u + 0x7fffu + ((u >> 16) & 1u)) >> 16;
    return (unsigned short)r;
}

static __device__ __forceinline__ float sgnf(float x) {
    return x > 0.0f ? 1.0f : (x < 0.0f ? -1.0f : 0.0f);
}

static __device__ __forceinline__ float ternf(float x) {
    return x > 0.3f ? 1.0f : (x < -0.3f ? -1.0f : 0.0f);
}

static __device__ __forceinline__ float bspline(float u) {
    float t = fabsf(u);
    if (t < 1.0f) return 0.66666666666666663f - t * t + 0.5f * t * t * t;
    if (t < 2.0f) { float w = 2.0f - t; return 0.16666666666666666f * w * w * w; }
    return 0.0f;
}

// ---------------- K0a: WT rows 0..255 = W1^T (bf16) ----------------
__global__ __launch_bounds__(256) void k_prep_w1t(const float* __restrict__ W1,
                                                  unsigned short* __restrict__ WT) {
    __shared__ float tile[32][33];
    int ktile = blockIdx.x;           // 0..31 (k tiles of 32)
    int ntile = blockIdx.y;           // 0..7  (n tiles of 32)
    int tx = threadIdx.x & 31;
    int ty = threadIdx.x >> 5;        // 0..7
#pragma unroll
    for (int i = 0; i < 4; ++i) {
        int k = ktile * 32 + ty + i * 8;
        int n = ntile * 32 + tx;
        tile[ty + i * 8][tx] = W1[(size_t)k * HH + n];   // coalesced over n
    }
    __syncthreads();
#pragma unroll
    for (int i = 0; i < 4; ++i) {
        int n = ntile * 32 + ty + i * 8;
        int k = ktile * 32 + tx;
        WT[(size_t)n * DD + k] = f2bf(tile[tx][ty + i * 8]);  // coalesced over k
    }
}

// ---------------- K0b: WT rows 256..287 = sign(directions) ----------------
__global__ __launch_bounds__(256) void k_prep_sig(const float* __restrict__ dirs,
                                                  unsigned short* __restrict__ WT) {
    int idx = blockIdx.x * 256 + threadIdx.x;     // 0..8191, 4 elems each
    float4 v = ((const float4*)dirs)[idx];
    ushort4 o;
    o.x = f2bf(sgnf(v.x)); o.y = f2bf(sgnf(v.y));
    o.z = f2bf(sgnf(v.z)); o.w = f2bf(sgnf(v.w));
    ((ushort4*)(WT + (size_t)HH * DD))[idx] = o;
}

// ---------------- K1: LayerNorm -> XN (bf16) ----------------
__global__ __launch_bounds__(256) void k_layernorm(const float* __restrict__ x,
                                                   const float* __restrict__ gamma,
                                                   const float* __restrict__ beta,
                                                   unsigned short* __restrict__ XN) {
    int row = blockIdx.x;
    int tid = threadIdx.x;
    const float4* xr = (const float4*)(x + (size_t)row * DD);
    float4 v = xr[tid];
    float s  = v.x + v.y + v.z + v.w;
    float sq = v.x * v.x + v.y * v.y + v.z * v.z + v.w * v.w;
#pragma unroll
    for (int off = 32; off; off >>= 1) {
        s  += __shfl_xor(s, off);
        sq += __shfl_xor(sq, off);
    }
    __shared__ float red[8];
    int wid = tid >> 6, lane = tid & 63;
    if (lane == 0) { red[wid] = s; red[wid + 4] = sq; }
    __syncthreads();
    s  = red[0] + red[1] + red[2] + red[3];
    sq = red[4] + red[5] + red[6] + red[7];
    float mu   = s * (1.0f / DD);
    float var  = sq * (1.0f / DD) - mu * mu;
    float rstd = rsqrtf(var + 1e-5f);
    float4 gm = ((const float4*)gamma)[tid];
    float4 bt = ((const float4*)beta)[tid];
    ushort4 o;
    o.x = f2bf((v.x - mu) * rstd * gm.x + bt.x);
    o.y = f2bf((v.y - mu) * rstd * gm.y + bt.y);
    o.z = f2bf((v.z - mu) * rstd * gm.z + bt.z);
    o.w = f2bf((v.w - mu) * rstd * gm.w + bt.w);
    ((ushort4*)(XN + (size_t)row * DD))[tid] = o;
}

// ---------------- K2: GEMM  HP[8192][288] = XN(bf16) @ WT(bf16)^T ----------------
// BM=128, BN=96, BK=64; 4 waves (2x2); wave tile 64x48 (Mf=4, Nf=3).
// LDS tiles row-stride 128B, XOR-swizzled: byte ^= ((row&7)<<4) on both the
// staged global source column and the ds_read address (rule 21: both sides).
__global__ __launch_bounds__(256) void k_gemm(const unsigned short* __restrict__ XN,
                                              const unsigned short* __restrict__ WT,
                                              float* __restrict__ HP) {
    __shared__ short Al[128 * 64];   // 16KB
    __shared__ short Bl[96 * 64];    // 12KB
    int tid = threadIdx.x;
    int colblk = blockIdx.x;         // 0..2
    int rowblk = blockIdx.y;         // 0..63
    int row0  = rowblk * 128;
    int ncol0 = colblk * 96;
    int lane = tid & 63;
    int wid  = tid >> 6;
    int wm = wid >> 1, wn = wid & 1;
    int l15 = lane & 15, l4 = lane >> 4;

    f32x4 acc[4][3];
#pragma unroll
    for (int i = 0; i < 4; ++i)
#pragma unroll
        for (int j = 0; j < 3; ++j) acc[i][j] = (f32x4){0.f, 0.f, 0.f, 0.f};

    for (int kt = 0; kt < 16; ++kt) {
        // stage A: 128x64 bf16 = 16KB = 4 issues of 256 lanes x 16B
#pragma unroll
        for (int ci = 0; ci < 4; ++ci) {
            int li = ci * 256 + tid;          // granule index (16B)
            int r  = li >> 3;                 // 0..127
            int g  = li & 7;
            int scol = (g * 8) ^ ((r & 7) << 3);   // inverse-swizzled source col (elems)
            const unsigned short* src = XN + (size_t)(row0 + r) * DD + kt * 64 + scol;
            __builtin_amdgcn_global_load_lds(
                (const __attribute__((address_space(1))) void*)(const void*)src,
                (__attribute__((address_space(3))) void*)(void*)(Al + li * 8), 16, 0, 0);
        }
        // stage B: 96x64 bf16 = 12KB = 3 issues
#pragma unroll
        for (int ci = 0; ci < 3; ++ci) {
            int li = ci * 256 + tid;          // 0..767
            int r  = li >> 3;                 // 0..95
            int g  = li & 7;
            int scol = (g * 8) ^ ((r & 7) << 3);
            const unsigned short* src = WT + (size_t)(ncol0 + r) * DD + kt * 64 + scol;
            __builtin_amdgcn_global_load_lds(
                (const __attribute__((address_space(1))) void*)(const void*)src,
                (__attribute__((address_space(3))) void*)(void*)(Bl + li * 8), 16, 0, 0);
        }
        __syncthreads();   // drains vmcnt before barrier (compiler-inserted)

#pragma unroll
        for (int ks = 0; ks < 2; ++ks) {
            bf16x8 avf[4], bvf[3];
#pragma unroll
            for (int mf = 0; mf < 4; ++mf) {
                int r = wm * 64 + mf * 16 + l15;
                int cb = (ks * 64 + l4 * 16) ^ ((r & 7) << 4);
                avf[mf] = *(const bf16x8*)((const char*)Al + r * 128 + cb);
            }
#pragma unroll
            for (int nf = 0; nf < 3; ++nf) {
                int r = wn * 48 + nf * 16 + l15;
                int cb = (ks * 64 + l4 * 16) ^ ((r & 7) << 4);
                bvf[nf] = *(const bf16x8*)((const char*)Bl + r * 128 + cb);
            }
#pragma unroll
            for (int mf = 0; mf < 4; ++mf)
#pragma unroll
                for (int nf = 0; nf < 3; ++nf)
                    acc[mf][nf] = __builtin_amdgcn_mfma_f32_16x16x32_bf16(
                        avf[mf], bvf[nf], acc[mf][nf], 0, 0, 0);
        }
        __syncthreads();
    }

    // epilogue: D frag layout col=lane&15, row=(lane>>4)*4+i  (guide §3, m89-verified)
#pragma unroll
    for (int mf = 0; mf < 4; ++mf) {
#pragma unroll
        for (int nf = 0; nf < 3; ++nf) {
            int colg  = ncol0 + wn * 48 + nf * 16 + l15;
            int rowg0 = row0 + wm * 64 + mf * 16 + l4 * 4;
#pragma unroll
            for (int i = 0; i < 4; ++i) {
                HP[(size_t)(rowg0 + i) * NCOLS + colg] = acc[mf][nf][i];
            }
        }
    }
}

// ---------------- K3: per-row epilogue + output ----------------
// 1 wave per row; block = 4 rows.
__global__ __launch_bounds__(256) void k_epilogue(
    const float* __restrict__ HP, const float* __restrict__ x,
    const float* __restrict__ positions, const int* __restrict__ states,
    const float* __restrict__ b1, const float* __restrict__ W2,
    const float* __restrict__ b2, const float* __restrict__ spc,
    const float* __restrict__ sps, const float* __restrict__ dirs,
    const float* __restrict__ ssig, const float* __restrict__ semb,
    const float* __restrict__ smod, const float* __restrict__ oscale,
    float* __restrict__ out) {
    int wid = threadIdx.x >> 6;
    int lane = threadIdx.x & 63;
    int row = blockIdx.x * 4 + wid;

    const float* hrow = HP + (size_t)row * NCOLS;
    float4 hv  = ((const float4*)hrow)[lane];          // h_pre[lane*4 .. +3]
    float4 b1v = ((const float4*)b1)[lane];
    float hs[4] = {hv.x, hv.y, hv.z, hv.w};
    float bs[4] = {b1v.x, b1v.y, b1v.z, b1v.w};
    float sa = 0.f, sb = 0.f;
#pragma unroll
    for (int i = 0; i < 4; ++i) {
        float h = hs[i] + bs[i];
        float g = 0.5f * h * (1.0f + erff(h * 0.70710678118654752f));  // exact gelu
        int j = lane * 4 + i;
        sa += g * W2[2 * j];
        sb += g * W2[2 * j + 1];
    }
#pragma unroll
    for (int off = 32; off; off >>= 1) {
        sa += __shfl_xor(sa, off);
        sb += __shfl_xor(sb, off);
    }
    float av = tanhf(sa + b2[0]);
    float bv = tanhf(sb + b2[1]);

    int st = states[row];
    float comb;
    if (lane < NTT) {
        float content = hrow[HH + lane];
        float pn = positions[row] * ((float)NTT / 2048.0f);
        float u  = (pn - (float)lane) * 0.5f;            // /SPREAD
        float spv = bspline(u);
        const float* sg = ssig + lane * 8;
        const float* se = semb + st * 8;
        float d0 = 0.f;
#pragma unroll
        for (int k = 0; k < 8; ++k) d0 += se[k] * sg[k];
        float temporal = 1.0f / (1.0f + expf(-d0));
        comb = content * spv * temporal;
    } else {
        comb = -__builtin_inff();
    }
    int bi = lane;
#pragma unroll
    for (int off = 32; off; off >>= 1) {
        float ov = __shfl_xor(comb, off);
        int   oi = __shfl_xor(bi, off);
        if (ov > comb || (ov == comb && oi < bi)) { comb = ov; bi = oi; }
    }
    // scalar spline math (redundant on all lanes)
    int ia = (int)((av + 1.0f) / 2.0f * 16.0f); ia = ia < 0 ? 0 : (ia > 15 ? 15 : ia);
    int ib = (int)((bv + 1.0f) / 2.0f * 16.0f); ib = ib < 0 ? 0 : (ib > 15 ? 15 : ib);
    const float* cc = spc + (((size_t)bi * 16 + ia) * 16 + ib) * 3;
    float c0 = ternf(cc[0]), c1 = ternf(cc[1]), c2 = ternf(cc[2]);
    const float csz = 0.125f;
    float la = (av + 1.0f - (float)ia * csz) * 8.0f;     // /cs
    float lb = (bv + 1.0f - (float)ib * csz) * 8.0f;
    float scale = (c0 + c1 * la + c2 * lb) * sps[bi];
    float sm = smod[st * NTT + bi];
    float cr = scale * sm * oscale[0];

    const float4* xr = (const float4*)(x + (size_t)row * DD);
    const float4* dr = (const float4*)(dirs + (size_t)bi * DD);
    float4* orow = (float4*)(out + (size_t)row * DD);
#pragma unroll
    for (int i = 0; i < 4; ++i) {
        int idx = i * 64 + lane;
        float4 xv = xr[idx];
        float4 dv = dr[idx];
        float4 o;
        o.x = fmaf(cr, dv.x, xv.x);
        o.y = fmaf(cr, dv.y, xv.y);
        o.z = fmaf(cr, dv.z, xv.z);
        o.w = fmaf(cr, dv.w, xv.w);
        orow[idx] = o;
    }
}

extern "C" void kernel_launch(void* const* d_in, const int* in_sizes, int n_in,
                              void* d_out, int out_size, void* d_ws, size_t ws_size,
                              hipStream_t stream) {
    const float* x     = (const float*)d_in[0];
    const float* pos   = (const float*)d_in[1];
    const int*   st    = (const int*)d_in[2];
    const float* gam   = (const float*)d_in[3];
    const float* bet   = (const float*)d_in[4];
    const float* W1    = (const float*)d_in[5];
    const float* b1    = (const float*)d_in[6];
    const float* W2    = (const float*)d_in[7];
    const float* b2    = (const float*)d_in[8];
    const float* spc   = (const float*)d_in[9];
    const float* sps   = (const float*)d_in[10];
    const float* dirs  = (const float*)d_in[11];
    const float* ssig  = (const float*)d_in[12];
    const float* semb  = (const float*)d_in[13];
    const float* smod  = (const float*)d_in[14];
    const float* oscal = (const float*)d_in[15];
    float* out = (float*)d_out;

    char* ws = (char*)d_ws;
    unsigned short* XN = (unsigned short*)ws;                         // 8192*1024 bf16 = 16 MiB
    unsigned short* WT = (unsigned short*)(ws + 16777216);            // 288*1024 bf16
    float*          HP = (float*)(ws + 17367040);                     // 8192*288 f32

    k_prep_w1t<<<dim3(32, 8), 256, 0, stream>>>(W1, WT);
    k_prep_sig<<<32, 256, 0, stream>>>(dirs, WT);
    k_layernorm<<<NROWS, 256, 0, stream>>>(x, gam, bet, XN);
    k_gemm<<<dim3(3, 64), 256, 0, stream>>>(XN, WT, HP);
    k_epilogue<<<NROWS / 4, 256, 0, stream>>>(HP, x, pos, st, b1, W2, b2, spc, sps,
                                              dirs, ssig, semb, smod, oscal, out);
}